// Round 19
// baseline (37.768 us; speedup 1.0000x reference)
//
#include <hip/hip_runtime.h>

#define BB 4
#define CC 32
#define HH 512
#define WW 500
#define SS 10
#define SW 50
#define NQ 125            // 125 float4 columns per row
#define CP 33             // padded LDS strip stride (bank spread)
#define PB 336            // padded partials row: 320 chan + 10 tex + 6 pad
#define RPB 8             // rows per block
#define NRB (HH / RPB)    // 64 row-tiles per image
#define NBLK1 (BB * NRB)  // 256 stage-1 blocks (1 per CU)

// ---------------- Stage 1: eight-row strip sums -> unique partial slot ----------------
// Identical to R17 (proven 34.8us total): one atomicAdd per channel covers 8 rows;
// g[8][4] static-idx gray regs; channel unroll 2 -> 16-load window (R13: bigger spills).
__global__ __launch_bounds__(128)
void pan_stage1(const float* __restrict__ x,
                float* __restrict__ partials)   // [NBLK1][PB]
{
    const int tid = threadIdx.x;
    const int blk = blockIdx.x;
    const int b   = blk >> 6;            // blk / NRB
    const int j   = blk & (NRB - 1);
    const bool active = (tid < NQ);
    const int w0  = 4 * tid;
    const int s0  = w0 / SW;
    const int s3  = (w0 + 3) / SW;
    const bool split = (s3 != s0) && active;   // boundary always at pixel offset 2

    __shared__ float lds_c[SS * CP];     // bank-padded
    __shared__ float lds_t[SS];
    for (int i = tid; i < SS * CP; i += 128) lds_c[i] = 0.0f;
    if (tid < SS) lds_t[tid] = 0.0f;
    __syncthreads();

    if (active) {
        const float* base = x + (size_t)b * CC * HH * WW + (size_t)(RPB * j) * WW + w0;
        float g[RPB][4];
#pragma unroll
        for (int r = 0; r < RPB; ++r)
#pragma unroll
            for (int p = 0; p < 4; ++p) g[r][p] = 0.0f;

#pragma unroll 2
        for (int c = 0; c < CC; ++c) {
            const float* pc = base + (size_t)c * HH * WW;
            float4 v[RPB];
#pragma unroll
            for (int r = 0; r < RPB; ++r)
                v[r] = *reinterpret_cast<const float4*>(pc + (size_t)r * WW);
            float lo = 0.0f, hi = 0.0f;
#pragma unroll
            for (int r = 0; r < RPB; ++r) {
                g[r][0] += v[r].x; g[r][1] += v[r].y;
                g[r][2] += v[r].z; g[r][3] += v[r].w;
                lo += v[r].x + v[r].y;
                hi += v[r].z + v[r].w;
            }
            atomicAdd(&lds_c[s0 * CP + c], lo + (split ? 0.0f : hi));
            if (split) atomicAdd(&lds_c[s3 * CP + c], hi);
        }

        float qlo = 0.0f, qhi = 0.0f;
#pragma unroll
        for (int r = 0; r < RPB; ++r) {
            qlo += g[r][0] * g[r][0] + g[r][1] * g[r][1];
            qhi += g[r][2] * g[r][2] + g[r][3] * g[r][3];
        }
        if (split) {
            atomicAdd(&lds_t[s0], qlo);
            atomicAdd(&lds_t[s3], qhi);
        } else {
            atomicAdd(&lds_t[s0], qlo + qhi);
        }
    }
    __syncthreads();

    float* dst = partials + (size_t)blk * PB;
    for (int i = tid; i < SS * CC; i += 128)
        dst[i] = lds_c[(i >> 5) * CP + (i & 31)];       // unpad -> contiguous
    if (tid < SS) dst[SS * CC + tid] = lds_t[tid];
}

// ---------------- Stage 2 (fused): partials-reduce + feats + hierarchy + loss + tree ----
// R17 post-mortem: stage1b (1320 tiny blocks) + separate stage2 + launch gaps cost
// ~8us fixed. Fused: phase A reduces the 344KB L2-resident partials in-block
// (1320 outputs x 64 rows, ~82 loads/thread, unroll-8 pipelined), then the proven
// phases read chan/tex from LDS. 3 dispatches -> 2.
__global__ __launch_bounds__(1024)
void pan_stage2(const float* __restrict__ partials,
                float* __restrict__ out)
{
    __shared__ float chan_s[BB * SS * CC];   // 1280
    __shared__ float tex_s[BB * SS];         // 40
    __shared__ float feats[BB][SS][CC];      // 1280
    __shared__ float cur1[BB][5][CC];        // 640
    __shared__ float cur2[BB][3][CC];        // 384
    __shared__ float cur3[BB][2][CC];        // 256
    __shared__ float cur4[BB][1][CC];        // 128
    __shared__ float red[1024];
    const int t = threadIdx.x;

    // phase A: column-reduce partials -> chan_s/tex_s (1320 outputs, strided)
    for (int o = t; o < BB * 330; o += 1024) {
        const int b  = o / 330;
        const int oo = o % 330;
        const float* col = partials + (size_t)b * NRB * PB + oo;
        float v = 0.0f;
#pragma unroll 8
        for (int k = 0; k < NRB; ++k) v += col[(size_t)k * PB];
        if (oo < SS * CC) chan_s[b * SS * CC + oo] = v;
        else              tex_s[b * SS + (oo - SS * CC)] = v;
    }
    __syncthreads();

    // feats = 0.5 * nodes + 0.5 * texture   (1280 elements, strided)
    for (int i = t; i < BB * SS * CC; i += 1024) {
        int b = i / (SS * CC);
        int s = (i / CC) % SS;
        float node    = chan_s[i] * (1.0f / (HH * SW));         // /25600
        float texture = tex_s[b * SS + s] * (1.0f / (CC * CC)); // tsum/1024
        ((float*)feats)[i] = 0.5f * node + 0.5f * texture;
    }
    __syncthreads();

    if (t < BB * 5 * CC) {   // 640
        int b = t / (5 * CC), j = (t / CC) % 5, c = t % CC;
        cur1[b][j][c] = 0.5f * (feats[b][2 * j][c] + feats[b][2 * j + 1][c]);
    }
    __syncthreads();
    if (t < BB * 3 * CC) {   // 384
        int b = t / (3 * CC), j = (t / CC) % 3, c = t % CC;
        cur2[b][j][c] = (j < 2) ? 0.5f * (cur1[b][2 * j][c] + cur1[b][2 * j + 1][c])
                                : cur1[b][4][c];
    }
    __syncthreads();
    if (t < BB * 2 * CC) {   // 256
        int b = t / (2 * CC), j = (t / CC) % 2, c = t % CC;
        cur3[b][j][c] = (j == 0) ? 0.5f * (cur2[b][0][c] + cur2[b][1][c])
                                 : cur2[b][2][c];
    }
    __syncthreads();
    if (t < BB * CC) {       // 128
        int b = t / CC, c = t % CC;
        cur4[b][0][c] = 0.5f * (cur3[b][0][c] + cur3[b][1][c]);
    }
    __syncthreads();

    // reg = sum of per-level means of cur^2
    float rp = 0.0f;
    for (int i = t; i < BB * 5 * CC; i += 1024) { float v = ((float*)cur1)[i]; rp += v * v * (1.0f / (BB * 5 * CC)); }
    for (int i = t; i < BB * 3 * CC; i += 1024) { float v = ((float*)cur2)[i]; rp += v * v * (1.0f / (BB * 3 * CC)); }
    for (int i = t; i < BB * 2 * CC; i += 1024) { float v = ((float*)cur3)[i]; rp += v * v * (1.0f / (BB * 2 * CC)); }
    for (int i = t; i < BB * 1 * CC; i += 1024) { float v = ((float*)cur4)[i]; rp += v * v * (1.0f / (BB * 1 * CC)); }

    // pairwise contrastive term over leaves (400 pairs)
    float lp = 0.0f;
    if (t < BB * SS * SS) {
        int b = t / (SS * SS), i = (t / SS) % SS, j = t % SS;
        float d2 = 0.0f;
#pragma unroll
        for (int c = 0; c < CC; ++c) {
            float df = feats[b][i][c] - feats[b][j][c];
            d2 += df * df;
        }
        float d = sqrtf(d2 + 1e-12f);
        int lev;
        if (i == j) lev = 0;
        else if ((i >> 1) == (j >> 1)) lev = 1;
        else {
            int g2i = (i < 4) ? 0 : ((i < 8) ? 1 : 2);
            int g2j = (j < 4) ? 0 : ((j < 8) ? 1 : 2);
            if (g2i == g2j) lev = 2;
            else if ((i < 8) == (j < 8)) lev = 3;
            else lev = 4;
        }
        float w = 1.0f - 0.25f * (float)lev;
        float m = fmaxf(1.0f - d, 0.0f);
        lp = w * d * d + (1.0f - w) * m * m;
    }

    // reduce pairwise sum
    red[t] = lp;
    __syncthreads();
    for (int off = 512; off >= 1; off >>= 1) {
        if (t < off) red[t] += red[t + off];
        __syncthreads();
    }
    float lsum = red[0];
    __syncthreads();
    // reduce reg partials
    red[t] = rp;
    __syncthreads();
    for (int off = 512; off >= 1; off >>= 1) {
        if (t < off) red[t] += red[t + off];
        __syncthreads();
    }
    if (t == 0) out[BB * 21 * 2] = lsum * (1.0f / (BB * SS * SS)) + 0.01f * red[0];

    // tree: [B, 21, 2] = (parent, level), written as float32 (168 elements)
    if (t < BB * 21 * 2) {
        int g = (t % 42) >> 1;
        int k = t & 1;
        int par, lv;
        if (g < 10)      { par = 10 + (g >> 1);        lv = 0; }
        else if (g < 15) { par = 15 + ((g - 10) >> 1); lv = 1; }
        else if (g < 18) { par = 18 + ((g - 15) >> 1); lv = 2; }
        else if (g < 20) { par = 20;                   lv = 3; }
        else             { par = 20;                   lv = 4; }
        out[t] = (float)(k ? lv : par);
    }
}

extern "C" void kernel_launch(void* const* d_in, const int* in_sizes, int n_in,
                              void* d_out, int out_size, void* d_ws, size_t ws_size,
                              hipStream_t stream) {
    const float* x = (const float*)d_in[0];
    float* out      = (float*)d_out;
    float* partials = (float*)d_ws;        // 256*336 floats = 344 KB

    // no memset needed: every ws element read is written first within this call
    pan_stage1<<<NBLK1, 128, 0, stream>>>(x, partials);
    pan_stage2<<<1, 1024, 0, stream>>>(partials, out);
}

// Round 20
// 34.403 us; speedup vs baseline: 1.0978x; 1.0978x over previous
//
#include <hip/hip_runtime.h>

#define BB 4
#define CC 32
#define HH 512
#define WW 500
#define SS 10
#define SW 50
#define NQ 125            // 125 float4 columns per row
#define CP 33             // padded LDS strip stride (bank spread)
#define PB 336            // padded partials row: 320 chan + 10 tex + 6 pad
#define RPB 4             // rows per block  (R16 optimum: RPB4=34.56us, RPB8=34.78, fused=37.8)
#define NRB (HH / RPB)    // 128 row-tiles per image
#define NBLK1 (BB * NRB)  // 512 stage-1 blocks

// ws layout (floats): partials[NBLK1][PB] | chan[BB*SS*CC] | tex[BB*SS]
#define WS_CHAN (NBLK1 * PB)
#define WS_TEX  (WS_CHAN + BB * SS * CC)

// ---------------- Stage 1: four-row strip sums -> unique partial slot ----------------
// R16 config (best measured). Amortization ladder: one LDS atomicAdd per channel
// covers 4 rows; g[4][4] static-idx gray regs; channel unroll 4 -> 16-load register
// window (R13: bigger windows spill to scratch; R11: per-thread csum[32] kills MLP).
// 512 blocks = 2 blocks/CU = 4 waves/CU; ~64KB in flight/CU covers HBM latency.
__global__ __launch_bounds__(128)
void pan_stage1(const float* __restrict__ x,
                float* __restrict__ partials)   // [NBLK1][PB]
{
    const int tid = threadIdx.x;
    const int blk = blockIdx.x;
    const int b   = blk >> 7;            // blk / NRB
    const int j   = blk & (NRB - 1);
    const bool active = (tid < NQ);
    const int w0  = 4 * tid;
    const int s0  = w0 / SW;
    const int s3  = (w0 + 3) / SW;
    const bool split = (s3 != s0) && active;   // boundary always at pixel offset 2

    __shared__ float lds_c[SS * CP];     // bank-padded
    __shared__ float lds_t[SS];
    for (int i = tid; i < SS * CP; i += 128) lds_c[i] = 0.0f;
    if (tid < SS) lds_t[tid] = 0.0f;
    __syncthreads();

    if (active) {
        const float* base = x + (size_t)b * CC * HH * WW + (size_t)(RPB * j) * WW + w0;
        float g[RPB][4];
#pragma unroll
        for (int r = 0; r < RPB; ++r)
#pragma unroll
            for (int p = 0; p < 4; ++p) g[r][p] = 0.0f;

#pragma unroll 4
        for (int c = 0; c < CC; ++c) {
            const float* pc = base + (size_t)c * HH * WW;
            float4 v[RPB];
#pragma unroll
            for (int r = 0; r < RPB; ++r)
                v[r] = *reinterpret_cast<const float4*>(pc + (size_t)r * WW);
            float lo = 0.0f, hi = 0.0f;
#pragma unroll
            for (int r = 0; r < RPB; ++r) {
                g[r][0] += v[r].x; g[r][1] += v[r].y;
                g[r][2] += v[r].z; g[r][3] += v[r].w;
                lo += v[r].x + v[r].y;
                hi += v[r].z + v[r].w;
            }
            atomicAdd(&lds_c[s0 * CP + c], lo + (split ? 0.0f : hi));
            if (split) atomicAdd(&lds_c[s3 * CP + c], hi);
        }

        float qlo = 0.0f, qhi = 0.0f;
#pragma unroll
        for (int r = 0; r < RPB; ++r) {
            qlo += g[r][0] * g[r][0] + g[r][1] * g[r][1];
            qhi += g[r][2] * g[r][2] + g[r][3] * g[r][3];
        }
        if (split) {
            atomicAdd(&lds_t[s0], qlo);
            atomicAdd(&lds_t[s3], qhi);
        } else {
            atomicAdd(&lds_t[s0], qlo + qhi);
        }
    }
    __syncthreads();

    float* dst = partials + (size_t)blk * PB;
    for (int i = tid; i < SS * CC; i += 128)
        dst[i] = lds_c[(i >> 5) * CP + (i & 31)];       // unpad -> contiguous
    if (tid < SS) dst[SS * CC + tid] = lds_t[tid];
}

// ---------------- Stage 1b: column-reduce partials -> chan/tex ----------------
// One wave per output: grid = BB*330; thread t sums rows t, t+64 of the image's
// 128 partial rows (L2-resident 688 KB), 6-step shuffle reduce, lane-0 store.
// R19 lesson: do NOT fuse this into a single block -- partials live in all 8 XCDs'
// L2s; a parallel 1320-block dispatch beats one CU pulling cross-XCD (+3us).
__global__ __launch_bounds__(64)
void pan_stage1b(const float* __restrict__ partials,
                 float* __restrict__ chan,   // [BB][SS][CC]
                 float* __restrict__ tex)    // [BB][SS]
{
    const int g = blockIdx.x;
    const int b = g / 330;
    const int o = g % 330;
    const int t = threadIdx.x;

    const float* col = partials + (size_t)b * NRB * PB + o;
    float v = col[(size_t)t * PB] + col[(size_t)(t + 64) * PB];
#pragma unroll
    for (int off = 32; off >= 1; off >>= 1) v += __shfl_xor(v, off, 64);
    if (t == 0) {
        if (o < SS * CC) chan[b * SS * CC + o] = v;
        else             tex[b * SS + (o - SS * CC)] = v;
    }
}

// ---------------- Stage 2: feats, hierarchy+reg, pairwise loss, tree ----------------
// 1024 threads; 1280-element phases use stride loops.
__global__ __launch_bounds__(1024)
void pan_stage2(const float* __restrict__ chan,
                const float* __restrict__ tex,
                float* __restrict__ out)
{
    __shared__ float feats[BB][SS][CC];   // 1280
    __shared__ float cur1[BB][5][CC];     // 640
    __shared__ float cur2[BB][3][CC];     // 384
    __shared__ float cur3[BB][2][CC];     // 256
    __shared__ float cur4[BB][1][CC];     // 128
    __shared__ float red[1024];
    const int t = threadIdx.x;

    // feats = 0.5 * nodes + 0.5 * texture   (1280 elements, strided)
    for (int i = t; i < BB * SS * CC; i += 1024) {
        int b = i / (SS * CC);
        int s = (i / CC) % SS;
        float node    = chan[i] * (1.0f / (HH * SW));         // /25600
        float texture = tex[b * SS + s] * (1.0f / (CC * CC)); // tsum/1024
        ((float*)feats)[i] = 0.5f * node + 0.5f * texture;
    }
    __syncthreads();

    if (t < BB * 5 * CC) {   // 640
        int b = t / (5 * CC), j = (t / CC) % 5, c = t % CC;
        cur1[b][j][c] = 0.5f * (feats[b][2 * j][c] + feats[b][2 * j + 1][c]);
    }
    __syncthreads();
    if (t < BB * 3 * CC) {   // 384
        int b = t / (3 * CC), j = (t / CC) % 3, c = t % CC;
        cur2[b][j][c] = (j < 2) ? 0.5f * (cur1[b][2 * j][c] + cur1[b][2 * j + 1][c])
                                : cur1[b][4][c];
    }
    __syncthreads();
    if (t < BB * 2 * CC) {   // 256
        int b = t / (2 * CC), j = (t / CC) % 2, c = t % CC;
        cur3[b][j][c] = (j == 0) ? 0.5f * (cur2[b][0][c] + cur2[b][1][c])
                                 : cur2[b][2][c];
    }
    __syncthreads();
    if (t < BB * CC) {       // 128
        int b = t / CC, c = t % CC;
        cur4[b][0][c] = 0.5f * (cur3[b][0][c] + cur3[b][1][c]);
    }
    __syncthreads();

    // reg = sum of per-level means of cur^2
    float rp = 0.0f;
    for (int i = t; i < BB * 5 * CC; i += 1024) { float v = ((float*)cur1)[i]; rp += v * v * (1.0f / (BB * 5 * CC)); }
    for (int i = t; i < BB * 3 * CC; i += 1024) { float v = ((float*)cur2)[i]; rp += v * v * (1.0f / (BB * 3 * CC)); }
    for (int i = t; i < BB * 2 * CC; i += 1024) { float v = ((float*)cur3)[i]; rp += v * v * (1.0f / (BB * 2 * CC)); }
    for (int i = t; i < BB * 1 * CC; i += 1024) { float v = ((float*)cur4)[i]; rp += v * v * (1.0f / (BB * 1 * CC)); }

    // pairwise contrastive term over leaves (400 pairs)
    float lp = 0.0f;
    if (t < BB * SS * SS) {
        int b = t / (SS * SS), i = (t / SS) % SS, j = t % SS;
        float d2 = 0.0f;
#pragma unroll
        for (int c = 0; c < CC; ++c) {
            float df = feats[b][i][c] - feats[b][j][c];
            d2 += df * df;
        }
        float d = sqrtf(d2 + 1e-12f);
        int lev;
        if (i == j) lev = 0;
        else if ((i >> 1) == (j >> 1)) lev = 1;
        else {
            int g2i = (i < 4) ? 0 : ((i < 8) ? 1 : 2);
            int g2j = (j < 4) ? 0 : ((j < 8) ? 1 : 2);
            if (g2i == g2j) lev = 2;
            else if ((i < 8) == (j < 8)) lev = 3;
            else lev = 4;
        }
        float w = 1.0f - 0.25f * (float)lev;
        float m = fmaxf(1.0f - d, 0.0f);
        lp = w * d * d + (1.0f - w) * m * m;
    }

    // reduce pairwise sum
    red[t] = lp;
    __syncthreads();
    for (int off = 512; off >= 1; off >>= 1) {
        if (t < off) red[t] += red[t + off];
        __syncthreads();
    }
    float lsum = red[0];
    __syncthreads();
    // reduce reg partials
    red[t] = rp;
    __syncthreads();
    for (int off = 512; off >= 1; off >>= 1) {
        if (t < off) red[t] += red[t + off];
        __syncthreads();
    }
    if (t == 0) out[BB * 21 * 2] = lsum * (1.0f / (BB * SS * SS)) + 0.01f * red[0];

    // tree: [B, 21, 2] = (parent, level), written as float32 (168 elements)
    if (t < BB * 21 * 2) {
        int g = (t % 42) >> 1;
        int k = t & 1;
        int par, lv;
        if (g < 10)      { par = 10 + (g >> 1);        lv = 0; }
        else if (g < 15) { par = 15 + ((g - 10) >> 1); lv = 1; }
        else if (g < 18) { par = 18 + ((g - 15) >> 1); lv = 2; }
        else if (g < 20) { par = 20;                   lv = 3; }
        else             { par = 20;                   lv = 4; }
        out[t] = (float)(k ? lv : par);
    }
}

extern "C" void kernel_launch(void* const* d_in, const int* in_sizes, int n_in,
                              void* d_out, int out_size, void* d_ws, size_t ws_size,
                              hipStream_t stream) {
    const float* x = (const float*)d_in[0];
    float* out      = (float*)d_out;
    float* ws       = (float*)d_ws;
    float* partials = ws;                  // 512*336 floats = 688 KB
    float* chan     = ws + WS_CHAN;        // 1280 floats
    float* tex      = ws + WS_TEX;         // 40 floats

    // no memset needed: every ws element read is written first within this call
    pan_stage1 <<<NBLK1, 128, 0, stream>>>(x, partials);
    pan_stage1b<<<BB * 330, 64, 0, stream>>>(partials, chan, tex);
    pan_stage2 <<<1, 1024, 0, stream>>>(chan, tex, out);
}